// Round 7
// baseline (2437.994 us; speedup 1.0000x reference)
//
#include <hip/hip_runtime.h>

#define N_TOK 8192
#define DIM   1024
#define HID   2048
#define NEXP  8
#define TOPK  2
#define BM 256
#define BN 256
#define BK 64
#define NTHREADS 512
#define MAXROWS (N_TOK*TOPK + NEXP*BM)   /* 18432 */
#define MAXRT   (MAXROWS/BM)             /* 72 row tiles */
#define NT_COL  (HID/BN)                 /* 8 col tiles */
#define NPAIR   (N_TOK*TOPK)             /* 16384 */

typedef float f32x4 __attribute__((ext_vector_type(4)));
typedef short bf16x8 __attribute__((ext_vector_type(8)));

static __device__ __forceinline__ unsigned short f2bf(float f){
    union { float f; unsigned u; } v; v.f = f;
    unsigned r = v.u + 0x7FFFu + ((v.u >> 16) & 1u);
    return (unsigned short)(r >> 16);
}
static __device__ __forceinline__ float bf2f(unsigned short u){
    union { unsigned u; float f; } v; v.u = ((unsigned)u) << 16;
    return v.f;
}

static __device__ __forceinline__ void gload_lds16(const void* g, void* l){
    __builtin_amdgcn_global_load_lds((const __attribute__((address_space(1))) void*)g,
                                     (__attribute__((address_space(3))) void*)l,
                                     16, 0, 0);
}

// ---------------- weight convert + transpose (coalesced):
// src [z][R][C] f32 -> dst [z][C][R] bf16; 64x64 tiles
__global__ __launch_bounds__(256) void cvt_transpose_moe(
    const float* __restrict__ src, unsigned short* __restrict__ dst, int R, int C)
{
    __shared__ float tile[64][65];
    const size_t plane = (size_t)R * C;
    const float* s = src + (size_t)blockIdx.z * plane;
    unsigned short* d = dst + (size_t)blockIdx.z * plane;
    const int c0 = blockIdx.x * 64, r0 = blockIdx.y * 64;
    const int tq = threadIdx.x & 15, tr = threadIdx.x >> 4;   // 16 x 16
    #pragma unroll
    for (int p = 0; p < 4; ++p) {
        int row = p*16 + tr;
        float4 v = *(const float4*)(s + (size_t)(r0 + row) * C + c0 + tq*4);
        tile[row][tq*4+0] = v.x; tile[row][tq*4+1] = v.y;
        tile[row][tq*4+2] = v.z; tile[row][tq*4+3] = v.w;
    }
    __syncthreads();
    #pragma unroll
    for (int p = 0; p < 4; ++p) {
        int orow = p*16 + tr;
        ushort4 o;
        o.x = f2bf(tile[tq*4+0][orow]);
        o.y = f2bf(tile[tq*4+1][orow]);
        o.z = f2bf(tile[tq*4+2][orow]);
        o.w = f2bf(tile[tq*4+3][orow]);
        *(ushort4*)(d + (size_t)(c0 + orow) * R + r0 + tq*4) = o;
    }
}

// ---------------- router: 1 wave per token (NO atomics)
__global__ __launch_bounds__(256) void router_moe(
    const float* __restrict__ x, const float* __restrict__ Wg, const float* __restrict__ bg,
    float* __restrict__ gate_probs, float* __restrict__ gate_mask,
    int* __restrict__ tk_e, float* __restrict__ tk_w)
{
    const int lane = threadIdx.x & 63;
    const int n = blockIdx.x * 4 + (threadIdx.x >> 6);
    const float* xr = x + (size_t)n * DIM;

    float acc[NEXP];
    #pragma unroll
    for (int e = 0; e < NEXP; ++e) acc[e] = 0.f;
    #pragma unroll 4
    for (int i = 0; i < DIM/64; ++i) {
        int d = i*64 + lane;
        float xv = xr[d];
        const float4* wrow = (const float4*)(Wg + (size_t)d * NEXP);
        float4 w0 = wrow[0], w1 = wrow[1];
        acc[0] += xv*w0.x; acc[1] += xv*w0.y; acc[2] += xv*w0.z; acc[3] += xv*w0.w;
        acc[4] += xv*w1.x; acc[5] += xv*w1.y; acc[6] += xv*w1.z; acc[7] += xv*w1.w;
    }
    #pragma unroll
    for (int off = 32; off > 0; off >>= 1) {
        #pragma unroll
        for (int e = 0; e < NEXP; ++e) acc[e] += __shfl_xor(acc[e], off, 64);
    }
    float lgt[NEXP];
    float mx = acc[0] + bg[0];
    #pragma unroll
    for (int e = 0; e < NEXP; ++e) { lgt[e] = acc[e] + bg[e]; mx = fmaxf(mx, lgt[e]); }
    float s = 0.f;
    #pragma unroll
    for (int e = 0; e < NEXP; ++e) { lgt[e] = expf(lgt[e] - mx); s += lgt[e]; }
    float inv = 1.f / s;
    #pragma unroll
    for (int e = 0; e < NEXP; ++e) lgt[e] *= inv;

    int i1 = 0;
    #pragma unroll
    for (int e = 1; e < NEXP; ++e) if (lgt[e] > lgt[i1]) i1 = e;
    int i2 = (i1 == 0) ? 1 : 0;
    #pragma unroll
    for (int e = 0; e < NEXP; ++e) if (e != i1 && lgt[e] > lgt[i2]) i2 = e;
    float wsum = lgt[i1] + lgt[i2] + 1e-8f;
    float w1n = lgt[i1] / wsum, w2n = lgt[i2] / wsum;

    if (lane < NEXP) {
        gate_probs[(size_t)n*NEXP + lane] = lgt[lane];
        gate_mask [(size_t)n*NEXP + lane] = (lane == i1) ? w1n : (lane == i2) ? w2n : 0.f;
    }
    if (lane == 0) {
        tk_e[n*TOPK]   = i1; tk_e[n*TOPK+1] = i2;
        tk_w[n*TOPK]   = w1n; tk_w[n*TOPK+1] = w2n;
    }
}

// ---------------- assign: single block, 16 waves, ballot-histogram slotting
__global__ __launch_bounds__(1024) void assign_moe(
    const int* __restrict__ tk_e,
    int* __restrict__ slot_row, int* __restrict__ pair_token,
    int* __restrict__ sched_e, int* __restrict__ sched_row,
    int* __restrict__ total_tiles)
{
    __shared__ int whist[16][NEXP];
    __shared__ int wbase[16][NEXP];
    const int w = threadIdx.x >> 6, lane = threadIdx.x & 63;
    const int PW = NPAIR / 16;                 // 1024 entries per wave
    const unsigned long long below = ((unsigned long long)1 << lane) - 1;

    int h[NEXP] = {0,0,0,0,0,0,0,0};
    for (int i = 0; i < PW/64; ++i) {
        int e = tk_e[w*PW + i*64 + lane];
        #pragma unroll
        for (int ee = 0; ee < NEXP; ++ee)
            h[ee] += __popcll(__ballot(e == ee));
    }
    if (lane == 0) {
        #pragma unroll
        for (int ee = 0; ee < NEXP; ++ee) whist[w][ee] = h[ee];
    }
    __syncthreads();

    if (threadIdx.x == 0) {
        int base = 0, t = 0, ebase[NEXP];
        for (int e = 0; e < NEXP; ++e) {
            int c = 0;
            for (int ww = 0; ww < 16; ++ww) c += whist[ww][e];
            ebase[e] = base;
            int nt = (c + BM - 1) / BM;
            for (int i = 0; i < nt; ++i) { sched_e[t] = e; sched_row[t] = base + i*BM; ++t; }
            base += nt * BM;
        }
        *total_tiles = t;
        for (int e = 0; e < NEXP; ++e) {
            int r = ebase[e];
            for (int ww = 0; ww < 16; ++ww) { wbase[ww][e] = r; r += whist[ww][e]; }
        }
    }
    __syncthreads();

    int run[NEXP];
    #pragma unroll
    for (int ee = 0; ee < NEXP; ++ee) run[ee] = wbase[w][ee];
    for (int i = 0; i < PW/64; ++i) {
        int idx = w*PW + i*64 + lane;
        int e = tk_e[idx];
        int myslot = 0;
        #pragma unroll
        for (int ee = 0; ee < NEXP; ++ee) {
            unsigned long long m = __ballot(e == ee);
            if (e == ee) myslot = run[ee] + __popcll(m & below);
            run[ee] += __popcll(m);
        }
        slot_row[idx] = myslot;
        pair_token[myslot] = idx;
    }
}

// ---------------- gather: pure copy, slots precomputed
__global__ __launch_bounds__(256) void gather_moe(
    const float* __restrict__ x, const int* __restrict__ slot_row,
    unsigned short* __restrict__ Xg)
{
    const int n = blockIdx.x;
    const int r0 = slot_row[n*TOPK], r1 = slot_row[n*TOPK+1];
    float4 xv = ((const float4*)(x + (size_t)n * DIM))[threadIdx.x];
    ushort4 b;
    b.x = f2bf(xv.x); b.y = f2bf(xv.y); b.z = f2bf(xv.z); b.w = f2bf(xv.w);
    ((ushort4*)(Xg + (size_t)r0 * DIM))[threadIdx.x] = b;
    ((ushort4*)(Xg + (size_t)r1 * DIM))[threadIdx.x] = b;
}

// ---------------- grouped GEMM: 256x256, BK=64, 8 waves, 4-phase/K-tile schedule,
// ring half-slots (slotA[mh], slotB[nh]) -> LDS 64KB -> 2 blocks/CU.
// Ledger (2 loads/half-stage): stage@p1(A0,B0) p2(B1) p3(A1);
// waits vmcnt(2)@p0end, vmcnt(4)@p1end, vmcnt(4)@p3end (last tile: 2/0/-).
#define PHASE_MFMA(MH, NH, BF) do {                                          \
    __builtin_amdgcn_s_setprio(1);                                           \
    _Pragma("unroll")                                                        \
    for (int mi = 0; mi < 4; ++mi)                                           \
        _Pragma("unroll")                                                    \
        for (int nb = 0; nb < 2; ++nb)                                       \
            _Pragma("unroll")                                                \
            for (int kk = 0; kk < 2; ++kk)                                   \
                acc[(MH)*4+mi][(NH)*2+nb] =                                  \
                    __builtin_amdgcn_mfma_f32_16x16x32_bf16(                 \
                        af[mi][kk], BF[nb][kk], acc[(MH)*4+mi][(NH)*2+nb],   \
                        0, 0, 0);                                            \
    __builtin_amdgcn_s_setprio(0);                                           \
} while (0)

template<int K, int MODE>
__global__ __launch_bounds__(512, 4) void gemm_moe(
    const unsigned short* __restrict__ A,    // [rows][K] bf16
    const unsigned short* __restrict__ Bt,   // [E][HID][K] bf16
    const float* __restrict__ bias,          // [E][HID]
    const int* __restrict__ sched_e, const int* __restrict__ sched_row,
    const int* __restrict__ total_tiles,
    unsigned short* __restrict__ Out,
    const int* __restrict__ pair_token)
{
    // T1: bijective XCD swizzle (576 % 8 == 0)
    const int nwg  = gridDim.x * gridDim.y;
    const int orig = blockIdx.y * gridDim.x + blockIdx.x;
    const int q = nwg >> 3, r8 = nwg & 7, xcd = orig & 7, lin = orig >> 3;
    const int wg = (xcd < r8 ? xcd*(q+1) : r8*(q+1) + (xcd-r8)*q) + lin;
    const int rt = wg / NT_COL, ct = wg % NT_COL;
    if (rt >= *total_tiles) return;

    const int e    = sched_e[rt];
    const int row0 = sched_row[rt];
    const int col0 = ct * BN;
    const unsigned short* Be = Bt + (size_t)e * HID * K;

    __shared__ __align__(1024) char lds[65536];
    char* ldsA = lds;            // [2 half-slot][128 idx * 128 B] = 32 KB
    char* ldsB = lds + 32768;    // same

    const int tid  = threadIdx.x;
    const int wv   = tid >> 6, lane = tid & 63;
    const int wr   = wv >> 2,  wc   = wv & 3;      // 2 x 4 wave grid, wave out 128x64
    const int lrow = lane & 15, lg  = lane >> 4;
    const int sr   = lane >> 3, si  = lane & 7;
    const int gc16 = si ^ sr;                      // pre-swizzled global 16B slot (T2)

    const unsigned short* Ab = A  + (size_t)row0 * K + gc16 * 8;
    const unsigned short* Bb = Be + (size_t)col0 * K + gc16 * 8;

    f32x4 acc[8][4] = {};
    bf16x8 af[4][2], b0f[2][2], b1f[2][2];

    // stage one half-tile (16KB = 2 gloads/thread) into fixed slot h
    auto STAGE_A = [&](int h, int t) {
        char* dst = ldsA + h*16384;
        #pragma unroll
        for (int j = 0; j < 2; ++j) {
            int c = wv*2 + j;
            int r = ((c>>3)<<7) + h*64 + ((c&7)<<3) + sr;
            gload_lds16(Ab + (size_t)r * K + t*BK, dst + c*1024);
        }
    };
    auto STAGE_B = [&](int h, int t) {
        char* dst = ldsB + h*16384;
        #pragma unroll
        for (int j = 0; j < 2; ++j) {
            int c = wv*2 + j;
            int idx = c*8 + sr;
            int gcol = ((idx>>5)<<6) + h*32 + (idx&31);
            gload_lds16(Bb + (size_t)gcol * K + t*BK, dst + c*1024);
        }
    };
    auto RD_A = [&](int mh) {                      // 8 ds_read_b128
        const char* base = ldsA + mh*16384;
        #pragma unroll
        for (int mi = 0; mi < 4; ++mi) {
            int idx = wr*64 + mi*16 + lrow;
            #pragma unroll
            for (int kk = 0; kk < 2; ++kk) {
                int s = (kk*4 + lg) ^ (idx & 7);
                af[mi][kk] = *(const bf16x8*)(base + idx*128 + s*16);
            }
        }
    };
    auto RD_B = [&](int nh, bf16x8 (*bf)[2]) {     // 4 ds_read_b128
        const char* base = ldsB + nh*16384;
        #pragma unroll
        for (int nb = 0; nb < 2; ++nb) {
            int idx = wc*32 + nb*16 + lrow;
            #pragma unroll
            for (int kk = 0; kk < 2; ++kk) {
                int s = (kk*4 + lg) ^ (idx & 7);
                bf[nb][kk] = *(const bf16x8*)(base + idx*128 + s*16);
            }
        }
    };
    auto BARRIER = [&]() {
        __builtin_amdgcn_sched_barrier(0);
        __builtin_amdgcn_s_barrier();
        __builtin_amdgcn_sched_barrier(0);
    };
    auto LGKM0 = [&]() {
        asm volatile("s_waitcnt lgkmcnt(0)" ::: "memory");
        __builtin_amdgcn_sched_barrier(0);
    };

    constexpr int NT = K / BK;          // K-tiles
    static_assert(NT >= 2, "need >=2 K-tiles");

    // prologue: queue [A(0,0) B(0,0) B(0,1) A(0,1)] -> drain first 4 loads
    STAGE_A(0, 0); STAGE_B(0, 0); STAGE_B(1, 0); STAGE_A(1, 0);
    asm volatile("s_waitcnt vmcnt(4)" ::: "memory");
    BARRIER();

    for (int t = 0; t < NT; ++t) {
        const bool pf = (t + 1 < NT);
        // p0: Q(mh0,nh0). Entry: A(t,0),B(t,0) complete; [B(t,1),A(t,1)] in flight.
        RD_A(0); RD_B(0, b0f);
        BARRIER(); LGKM0();
        PHASE_MFMA(0,0,b0f);
        asm volatile("s_waitcnt vmcnt(2)" ::: "memory");   // drain B(t,1) for p1
        BARRIER();
        // p1: Q(mh0,nh1). slotA0/slotB0 free (read at p0) -> stage t+1 halves.
        RD_B(1, b1f);
        if (pf) { STAGE_A(0, t+1); STAGE_B(0, t+1); }
        BARRIER(); LGKM0();
        PHASE_MFMA(0,1,b1f);
        if (pf) { asm volatile("s_waitcnt vmcnt(4)" ::: "memory"); }  // drain A(t,1)
        else    { asm volatile("s_waitcnt vmcnt(0)" ::: "memory"); }
        BARRIER();
        // p2: Q(mh1,nh0). slotB1 free -> stage B(t+1,1).
        RD_A(1);
        if (pf) STAGE_B(1, t+1);
        BARRIER(); LGKM0();
        PHASE_MFMA(1,0,b0f);
        BARRIER();
        // p3: Q(mh1,nh1), no ds_reads. slotA1 free -> stage A(t+1,1).
        if (pf) STAGE_A(1, t+1);
        BARRIER();
        PHASE_MFMA(1,1,b1f);
        // drain A(t+1,0),B(t+1,0) for next p0 (8 outstanding -> 4)
        if (pf) { asm volatile("s_waitcnt vmcnt(4)" ::: "memory"); BARRIER(); }
    }

    // epilogue: C/D layout col=lane&15, row=(lane>>4)*4+reg
    if constexpr (MODE == 0) {
        #pragma unroll
        for (int nb = 0; nb < 4; ++nb) {
            int col = col0 + wc*64 + nb*16 + lrow;
            float bv = bias[(size_t)e*HID + col];
            #pragma unroll
            for (int mb = 0; mb < 8; ++mb) {
                int rb = row0 + wr*128 + mb*16 + lg*4;
                #pragma unroll
                for (int j = 0; j < 4; ++j) {
                    float v = fmaxf(acc[mb][nb][j] + bv, 0.f);
                    Out[(size_t)(rb + j) * HID + col] = f2bf(v);
                }
            }
        }
    } else {
        float bv[4]; int cols[4];
        #pragma unroll
        for (int nb = 0; nb < 4; ++nb) {
            cols[nb] = col0 + wc*64 + nb*16 + lrow;
            bv[nb] = bias[(size_t)e*HID + cols[nb]];
        }
        #pragma unroll
        for (int mb = 0; mb < 8; ++mb) {
            #pragma unroll
            for (int j = 0; j < 4; ++j) {
                int r = row0 + wr*128 + mb*16 + lg*4 + j;
                int pair = pair_token[r];
                if (pair < 0) continue;
                size_t prow = (size_t)(pair & 1) * N_TOK + (pair >> 1);
                #pragma unroll
                for (int nb = 0; nb < 4; ++nb)
                    Out[prow * HID + cols[nb]] = f2bf(acc[mb][nb][j] + bv[nb]);
            }
        }
    }
}

// ---------------- combine: out[n] = w0*P[0][n] + w1*P[1][n]
__global__ __launch_bounds__(256) void combine_moe(
    const unsigned short* __restrict__ P, const float* __restrict__ tk_w,
    float* __restrict__ out)
{
    const int n = blockIdx.x;
    const float w0 = tk_w[n*2], w1 = tk_w[n*2+1];
    const int c = threadIdx.x * 8;
    bf16x8 a = *(const bf16x8*)(P + (size_t)n * HID + c);
    bf16x8 b = *(const bf16x8*)(P + (size_t)(N_TOK + n) * HID + c);
    float4 o0, o1;
    float* op = &o0.x;
    #pragma unroll
    for (int i = 0; i < 4; ++i)
        op[i] = w0 * bf2f((unsigned short)a[i]) + w1 * bf2f((unsigned short)b[i]);
    float* op1 = &o1.x;
    #pragma unroll
    for (int i = 0; i < 4; ++i)
        op1[i] = w0 * bf2f((unsigned short)a[4+i]) + w1 * bf2f((unsigned short)b[4+i]);
    float4* dst = (float4*)(out + (size_t)n * HID + c);
    dst[0] = o0; dst[1] = o1;
}

extern "C" void kernel_launch(void* const* d_in, const int* in_sizes, int n_in,
                              void* d_out, int out_size, void* d_ws, size_t ws_size,
                              hipStream_t stream)
{
    const float* x  = (const float*)d_in[0];
    const float* Wg = (const float*)d_in[1];
    const float* bg = (const float*)d_in[2];
    const float* W1 = (const float*)d_in[3];
    const float* b1 = (const float*)d_in[4];
    const float* W2 = (const float*)d_in[5];
    const float* b2 = (const float*)d_in[6];

    float* out        = (float*)d_out;                       // [N, HID]
    float* gate_probs = out + (size_t)N_TOK * HID;           // [N, E]
    float* gate_mask  = gate_probs + (size_t)N_TOK * NEXP;   // [N, E]

    // workspace carve; P aliases dead W1t+Xg after GEMM1
    char* p = (char*)d_ws;
    auto carve = [&](size_t bytes) { char* r = p; p += (bytes + 255) & ~(size_t)255; return r; };
    unsigned short* W2t = (unsigned short*)carve((size_t)NEXP*HID*HID*2);  // 64 MB [e][j][h]
    unsigned short* Hb  = (unsigned short*)carve((size_t)MAXROWS*HID*2);   // 72 MB
    unsigned short* W1t = (unsigned short*)carve((size_t)NEXP*DIM*HID*2);  // 32 MB [e][h][d]
    unsigned short* Xg  = (unsigned short*)carve((size_t)MAXROWS*DIM*2);   // 36 MB
    unsigned short* P   = W1t;   // 64 MB alias over W1t+Xg; both dead at GEMM2
    int*   pair_token = (int*)  carve((size_t)MAXROWS*4);
    int*   slot_row   = (int*)  carve((size_t)NPAIR*4);
    int*   tk_e       = (int*)  carve((size_t)NPAIR*4);
    float* tk_w       = (float*)carve((size_t)NPAIR*4);
    int*   sched_e    = (int*)  carve(1024);
    int*   sched_row  = (int*)  carve(1024);
    int*   total_tiles= (int*)  carve(256);

    hipMemsetAsync(pair_token, 0xFF, (size_t)MAXROWS*4, stream);  // -1 = pad

    cvt_transpose_moe<<<dim3(HID/64, DIM/64, NEXP), 256, 0, stream>>>(W1, W1t, DIM, HID);
    cvt_transpose_moe<<<dim3(HID/64, HID/64, NEXP), 256, 0, stream>>>(W2, W2t, HID, HID);
    router_moe<<<N_TOK/4, 256, 0, stream>>>(x, Wg, bg, gate_probs, gate_mask, tk_e, tk_w);
    assign_moe<<<1, 1024, 0, stream>>>(tk_e, slot_row, pair_token,
                                       sched_e, sched_row, total_tiles);
    gather_moe<<<N_TOK, 256, 0, stream>>>(x, slot_row, Xg);
    gemm_moe<DIM, 0><<<dim3(MAXRT, NT_COL), NTHREADS, 0, stream>>>(
        Xg, W1t, b1, sched_e, sched_row, total_tiles, Hb, nullptr);
    gemm_moe<HID, 1><<<dim3(MAXRT, NT_COL), NTHREADS, 0, stream>>>(
        Hb, W2t, b2, sched_e, sched_row, total_tiles, P, pair_token);
    combine_moe<<<N_TOK, 256, 0, stream>>>(P, tk_w, out);
}

// Round 8
// 387.052 us; speedup vs baseline: 6.2989x; 6.2989x over previous
//
#include <hip/hip_runtime.h>

#define N_TOK 8192
#define DIM   1024
#define HID   2048
#define NEXP  8
#define TOPK  2
#define BM 256
#define BN 128
#define BK 64
#define NTHREADS 512
#define MAXROWS (N_TOK*TOPK + NEXP*BM)   /* 18432 */
#define MAXRT   (MAXROWS/BM)             /* 72 row tiles */
#define NT_COL  (HID/BN)                 /* 16 col tiles */
#define NPAIR   (N_TOK*TOPK)             /* 16384 */

typedef float f32x4 __attribute__((ext_vector_type(4)));
typedef short bf16x8 __attribute__((ext_vector_type(8)));

static __device__ __forceinline__ unsigned short f2bf(float f){
    union { float f; unsigned u; } v; v.f = f;
    unsigned r = v.u + 0x7FFFu + ((v.u >> 16) & 1u);
    return (unsigned short)(r >> 16);
}
static __device__ __forceinline__ float bf2f(unsigned short u){
    union { unsigned u; float f; } v; v.u = ((unsigned)u) << 16;
    return v.f;
}

static __device__ __forceinline__ void gload_lds16(const void* g, void* l){
    __builtin_amdgcn_global_load_lds((const __attribute__((address_space(1))) void*)g,
                                     (__attribute__((address_space(3))) void*)l,
                                     16, 0, 0);
}

// ---------------- weight convert + transpose (coalesced):
// src [z][R][C] f32 -> dst [z][C][R] bf16; 64x64 tiles
__global__ __launch_bounds__(256) void cvt_transpose_moe(
    const float* __restrict__ src, unsigned short* __restrict__ dst, int R, int C)
{
    __shared__ float tile[64][65];
    const size_t plane = (size_t)R * C;
    const float* s = src + (size_t)blockIdx.z * plane;
    unsigned short* d = dst + (size_t)blockIdx.z * plane;
    const int c0 = blockIdx.x * 64, r0 = blockIdx.y * 64;
    const int tq = threadIdx.x & 15, tr = threadIdx.x >> 4;   // 16 x 16
    #pragma unroll
    for (int p = 0; p < 4; ++p) {
        int row = p*16 + tr;
        float4 v = *(const float4*)(s + (size_t)(r0 + row) * C + c0 + tq*4);
        tile[row][tq*4+0] = v.x; tile[row][tq*4+1] = v.y;
        tile[row][tq*4+2] = v.z; tile[row][tq*4+3] = v.w;
    }
    __syncthreads();
    #pragma unroll
    for (int p = 0; p < 4; ++p) {
        int orow = p*16 + tr;
        ushort4 o;
        o.x = f2bf(tile[tq*4+0][orow]);
        o.y = f2bf(tile[tq*4+1][orow]);
        o.z = f2bf(tile[tq*4+2][orow]);
        o.w = f2bf(tile[tq*4+3][orow]);
        *(ushort4*)(d + (size_t)(c0 + orow) * R + r0 + tq*4) = o;
    }
}

// ---------------- router: 1 wave per token (NO atomics)
__global__ __launch_bounds__(256) void router_moe(
    const float* __restrict__ x, const float* __restrict__ Wg, const float* __restrict__ bg,
    float* __restrict__ gate_probs, float* __restrict__ gate_mask,
    int* __restrict__ tk_e, float* __restrict__ tk_w)
{
    const int lane = threadIdx.x & 63;
    const int n = blockIdx.x * 4 + (threadIdx.x >> 6);
    const float* xr = x + (size_t)n * DIM;

    float acc[NEXP];
    #pragma unroll
    for (int e = 0; e < NEXP; ++e) acc[e] = 0.f;
    #pragma unroll 4
    for (int i = 0; i < DIM/64; ++i) {
        int d = i*64 + lane;
        float xv = xr[d];
        const float4* wrow = (const float4*)(Wg + (size_t)d * NEXP);
        float4 w0 = wrow[0], w1 = wrow[1];
        acc[0] += xv*w0.x; acc[1] += xv*w0.y; acc[2] += xv*w0.z; acc[3] += xv*w0.w;
        acc[4] += xv*w1.x; acc[5] += xv*w1.y; acc[6] += xv*w1.z; acc[7] += xv*w1.w;
    }
    #pragma unroll
    for (int off = 32; off > 0; off >>= 1) {
        #pragma unroll
        for (int e = 0; e < NEXP; ++e) acc[e] += __shfl_xor(acc[e], off, 64);
    }
    float lgt[NEXP];
    float mx = acc[0] + bg[0];
    #pragma unroll
    for (int e = 0; e < NEXP; ++e) { lgt[e] = acc[e] + bg[e]; mx = fmaxf(mx, lgt[e]); }
    float s = 0.f;
    #pragma unroll
    for (int e = 0; e < NEXP; ++e) { lgt[e] = expf(lgt[e] - mx); s += lgt[e]; }
    float inv = 1.f / s;
    #pragma unroll
    for (int e = 0; e < NEXP; ++e) lgt[e] *= inv;

    int i1 = 0;
    #pragma unroll
    for (int e = 1; e < NEXP; ++e) if (lgt[e] > lgt[i1]) i1 = e;
    int i2 = (i1 == 0) ? 1 : 0;
    #pragma unroll
    for (int e = 0; e < NEXP; ++e) if (e != i1 && lgt[e] > lgt[i2]) i2 = e;
    float wsum = lgt[i1] + lgt[i2] + 1e-8f;
    float w1n = lgt[i1] / wsum, w2n = lgt[i2] / wsum;

    if (lane < NEXP) {
        gate_probs[(size_t)n*NEXP + lane] = lgt[lane];
        gate_mask [(size_t)n*NEXP + lane] = (lane == i1) ? w1n : (lane == i2) ? w2n : 0.f;
    }
    if (lane == 0) {
        tk_e[n*TOPK]   = i1; tk_e[n*TOPK+1] = i2;
        tk_w[n*TOPK]   = w1n; tk_w[n*TOPK+1] = w2n;
    }
}

// ---------------- assign: single block, 16 waves, ballot-histogram slotting
__global__ __launch_bounds__(1024) void assign_moe(
    const int* __restrict__ tk_e,
    int* __restrict__ slot_row, int* __restrict__ pair_token,
    int* __restrict__ sched_e, int* __restrict__ sched_row,
    int* __restrict__ total_tiles)
{
    __shared__ int whist[16][NEXP];
    __shared__ int wbase[16][NEXP];
    const int w = threadIdx.x >> 6, lane = threadIdx.x & 63;
    const int PW = NPAIR / 16;                 // 1024 entries per wave
    const unsigned long long below = ((unsigned long long)1 << lane) - 1;

    int h[NEXP] = {0,0,0,0,0,0,0,0};
    for (int i = 0; i < PW/64; ++i) {
        int e = tk_e[w*PW + i*64 + lane];
        #pragma unroll
        for (int ee = 0; ee < NEXP; ++ee)
            h[ee] += __popcll(__ballot(e == ee));
    }
    if (lane == 0) {
        #pragma unroll
        for (int ee = 0; ee < NEXP; ++ee) whist[w][ee] = h[ee];
    }
    __syncthreads();

    if (threadIdx.x == 0) {
        int base = 0, t = 0, ebase[NEXP];
        for (int e = 0; e < NEXP; ++e) {
            int c = 0;
            for (int ww = 0; ww < 16; ++ww) c += whist[ww][e];
            ebase[e] = base;
            int nt = (c + BM - 1) / BM;
            for (int i = 0; i < nt; ++i) { sched_e[t] = e; sched_row[t] = base + i*BM; ++t; }
            base += nt * BM;
        }
        *total_tiles = t;
        for (int e = 0; e < NEXP; ++e) {
            int r = ebase[e];
            for (int ww = 0; ww < 16; ++ww) { wbase[ww][e] = r; r += whist[ww][e]; }
        }
    }
    __syncthreads();

    int run[NEXP];
    #pragma unroll
    for (int ee = 0; ee < NEXP; ++ee) run[ee] = wbase[w][ee];
    for (int i = 0; i < PW/64; ++i) {
        int idx = w*PW + i*64 + lane;
        int e = tk_e[idx];
        int myslot = 0;
        #pragma unroll
        for (int ee = 0; ee < NEXP; ++ee) {
            unsigned long long m = __ballot(e == ee);
            if (e == ee) myslot = run[ee] + __popcll(m & below);
            run[ee] += __popcll(m);
        }
        slot_row[idx] = myslot;
        pair_token[myslot] = idx;
    }
}

// ---------------- gather: pure copy, slots precomputed
__global__ __launch_bounds__(256) void gather_moe(
    const float* __restrict__ x, const int* __restrict__ slot_row,
    unsigned short* __restrict__ Xg)
{
    const int n = blockIdx.x;
    const int r0 = slot_row[n*TOPK], r1 = slot_row[n*TOPK+1];
    float4 xv = ((const float4*)(x + (size_t)n * DIM))[threadIdx.x];
    ushort4 b;
    b.x = f2bf(xv.x); b.y = f2bf(xv.y); b.z = f2bf(xv.z); b.w = f2bf(xv.w);
    ((ushort4*)(Xg + (size_t)r0 * DIM))[threadIdx.x] = b;
    ((ushort4*)(Xg + (size_t)r1 * DIM))[threadIdx.x] = b;
}

// ---------------- grouped GEMM: 256x128 tile, BK=64, 8 waves (64x64 each),
// 4-phase quadrant schedule, ring half-slots: A 2x16KB + B 2x8KB = 48KB LDS
// -> 2 blocks/CU (launch_bounds(512,2): observed semantics = blocks/CU, reg clamp 128).
// Halves interleaved by bit5: A-half mh = rows with bit5==mh; B-half nh likewise.
// Per-thread loads: STAGE_A = 2, STAGE_B = 1.
// Ledger (steady tile t, per wave):
//   entry p0: A0,B0(t) done; [B1(t)1, A1(t)2] in flight
//   p0end vmcnt(2)  -> B1(t) ready
//   p1: stage A0(t+1)2 + B0(t+1)1 ; p1end vmcnt(3) -> A1(t) ready
//   p2: stage B1(t+1)1 ; p3: stage A1(t+1)2 ; p3end vmcnt(3) -> A0,B0(t+1) ready
// Last tile: p0end vmcnt(2); p1end vmcnt(0); no stages, no further waits.
#define PHASE_MFMA(MH, NH, BF) do {                                          \
    __builtin_amdgcn_s_setprio(1);                                           \
    _Pragma("unroll")                                                        \
    for (int mi = 0; mi < 2; ++mi)                                           \
        _Pragma("unroll")                                                    \
        for (int nb = 0; nb < 2; ++nb)                                       \
            _Pragma("unroll")                                                \
            for (int kk = 0; kk < 2; ++kk)                                   \
                acc[(MH)*2+mi][(NH)*2+nb] =                                  \
                    __builtin_amdgcn_mfma_f32_16x16x32_bf16(                 \
                        af[mi][kk], BF[nb][kk], acc[(MH)*2+mi][(NH)*2+nb],   \
                        0, 0, 0);                                            \
    __builtin_amdgcn_s_setprio(0);                                           \
} while (0)

template<int K, int MODE>
__global__ __launch_bounds__(512, 2) void gemm_moe(
    const unsigned short* __restrict__ A,    // [rows][K] bf16
    const unsigned short* __restrict__ Bt,   // [E][HID][K] bf16
    const float* __restrict__ bias,          // [E][HID]
    const int* __restrict__ sched_e, const int* __restrict__ sched_row,
    const int* __restrict__ total_tiles,
    unsigned short* __restrict__ Out,
    const int* __restrict__ pair_token)
{
    // T1: bijective XCD swizzle (1152 % 8 == 0)
    const int nwg  = gridDim.x * gridDim.y;
    const int orig = blockIdx.y * gridDim.x + blockIdx.x;
    const int q = nwg >> 3, r8 = nwg & 7, xcd = orig & 7, lin = orig >> 3;
    const int wg = (xcd < r8 ? xcd*(q+1) : r8*(q+1) + (xcd-r8)*q) + lin;
    const int rt = wg / NT_COL, ct = wg % NT_COL;
    if (rt >= *total_tiles) return;

    const int e    = sched_e[rt];
    const int row0 = sched_row[rt];
    const int col0 = ct * BN;
    const unsigned short* Be = Bt + (size_t)e * HID * K;

    __shared__ __align__(1024) char lds[49152];
    char* ldsA = lds;            // 2 half-slots x 16 KB (128 idx x 128 B)
    char* ldsB = lds + 32768;    // 2 half-slots x 8 KB  (64 idx x 128 B)

    const int tid  = threadIdx.x;
    const int wv   = tid >> 6, lane = tid & 63;
    const int wr   = wv >> 1,  wc   = wv & 1;      // 4 x 2 wave grid, wave out 64x64
    const int lrow = lane & 15, lg  = lane >> 4;
    const int sr   = lane >> 3, si  = lane & 7;
    const int gc16 = si ^ sr;                      // pre-swizzled global 16B slot (T2)

    const unsigned short* Ab = A  + (size_t)row0 * K + gc16 * 8;
    const unsigned short* Bb = Be + (size_t)col0 * K + gc16 * 8;

    f32x4 acc[4][4] = {};
    bf16x8 af[2][2], b0f[2][2], b1f[2][2];

    // A-half mh: 16 chunks of 1KB; slot idx = c*8+sr; row = (idx>>5)*64 + mh*32 + (idx&31)
    auto STAGE_A = [&](int h, int t) {
        char* dst = ldsA + h*16384;
        #pragma unroll
        for (int j = 0; j < 2; ++j) {
            int c = wv*2 + j;
            int idx = c*8 + sr;
            int r = ((idx>>5)<<6) + h*32 + (idx&31);
            gload_lds16(Ab + (size_t)r * K + t*BK, dst + c*1024);
        }
    };
    // B-half nh: 8 chunks of 1KB; slot idx = c*8+sr; col = (idx>>5)*64 + nh*32 + (idx&31)
    auto STAGE_B = [&](int h, int t) {
        char* dst = ldsB + h*8192;
        int c = wv;
        int idx = c*8 + sr;
        int gcol = ((idx>>5)<<6) + h*32 + (idx&31);
        gload_lds16(Bb + (size_t)gcol * K + t*BK, dst + c*1024);
    };
    auto RD_A = [&](int mh) {                      // 4 ds_read_b128
        const char* base = ldsA + mh*16384;
        #pragma unroll
        for (int mi = 0; mi < 2; ++mi) {
            int idx = wr*32 + mi*16 + lrow;
            #pragma unroll
            for (int kk = 0; kk < 2; ++kk) {
                int s = (kk*4 + lg) ^ (idx & 7);
                af[mi][kk] = *(const bf16x8*)(base + idx*128 + s*16);
            }
        }
    };
    auto RD_B = [&](int nh, bf16x8 (*bf)[2]) {     // 4 ds_read_b128
        const char* base = ldsB + nh*8192;
        #pragma unroll
        for (int nb = 0; nb < 2; ++nb) {
            int idx = wc*32 + nb*16 + lrow;
            #pragma unroll
            for (int kk = 0; kk < 2; ++kk) {
                int s = (kk*4 + lg) ^ (idx & 7);
                bf[nb][kk] = *(const bf16x8*)(base + idx*128 + s*16);
            }
        }
    };
    auto BARRIER = [&]() {
        __builtin_amdgcn_sched_barrier(0);
        __builtin_amdgcn_s_barrier();
        __builtin_amdgcn_sched_barrier(0);
    };
    auto LGKM0 = [&]() {
        asm volatile("s_waitcnt lgkmcnt(0)" ::: "memory");
        __builtin_amdgcn_sched_barrier(0);
    };

    constexpr int NT = K / BK;
    static_assert(NT >= 2, "need >=2 K-tiles");

    // prologue: issue [A0(2) B0(1) B1(1) A1(2)] for tile 0; drain first 3
    STAGE_A(0, 0); STAGE_B(0, 0); STAGE_B(1, 0); STAGE_A(1, 0);
    asm volatile("s_waitcnt vmcnt(3)" ::: "memory");
    BARRIER();

    for (int t = 0; t < NT; ++t) {
        const bool pf = (t + 1 < NT);
        // p0: Q(mh0,nh0)
        RD_A(0); RD_B(0, b0f);
        BARRIER(); LGKM0();
        PHASE_MFMA(0,0,b0f);
        asm volatile("s_waitcnt vmcnt(2)" ::: "memory");   // B1(t) ready
        BARRIER();
        // p1: Q(mh0,nh1); slots A0/B0 free -> stage t+1
        RD_B(1, b1f);
        if (pf) { STAGE_A(0, t+1); STAGE_B(0, t+1); }
        BARRIER(); LGKM0();
        PHASE_MFMA(0,1,b1f);
        if (pf) { asm volatile("s_waitcnt vmcnt(3)" ::: "memory"); }  // A1(t) ready
        else    { asm volatile("s_waitcnt vmcnt(0)" ::: "memory"); }
        BARRIER();
        // p2: Q(mh1,nh0); slot B1 free -> stage B1(t+1)
        RD_A(1);
        if (pf) STAGE_B(1, t+1);
        BARRIER(); LGKM0();
        PHASE_MFMA(1,0,b0f);
        BARRIER();
        // p3: Q(mh1,nh1), no ds_reads; slot A1 free -> stage A1(t+1)
        if (pf) STAGE_A(1, t+1);
        BARRIER();
        PHASE_MFMA(1,1,b1f);
        // entering next p0: need A0,B0(t+1) -> leave [B1(1),A1(2)] in flight
        if (pf) { asm volatile("s_waitcnt vmcnt(3)" ::: "memory"); BARRIER(); }
    }

    // epilogue: acc[m][n] -> row = wr*64 + (m>>1)*32 + (m&1)*16 + lg*4 + j
    //                       col = wc*64 + (n>>1)*32 + (n&1)*16 + lrow
    if constexpr (MODE == 0) {
        #pragma unroll
        for (int n = 0; n < 4; ++n) {
            int col = col0 + wc*64 + ((n>>1)<<5) + ((n&1)<<4) + lrow;
            float bv = bias[(size_t)e*HID + col];
            #pragma unroll
            for (int m = 0; m < 4; ++m) {
                int rb = row0 + wr*64 + ((m>>1)<<5) + ((m&1)<<4) + lg*4;
                #pragma unroll
                for (int j = 0; j < 4; ++j) {
                    float v = fmaxf(acc[m][n][j] + bv, 0.f);
                    Out[(size_t)(rb + j) * HID + col] = f2bf(v);
                }
            }
        }
    } else {
        float bv[4]; int cols[4];
        #pragma unroll
        for (int n = 0; n < 4; ++n) {
            cols[n] = col0 + wc*64 + ((n>>1)<<5) + ((n&1)<<4) + lrow;
            bv[n] = bias[(size_t)e*HID + cols[n]];
        }
        #pragma unroll
        for (int m = 0; m < 4; ++m) {
            #pragma unroll
            for (int j = 0; j < 4; ++j) {
                int r = row0 + wr*64 + ((m>>1)<<5) + ((m&1)<<4) + lg*4 + j;
                int pair = pair_token[r];
                if (pair < 0) continue;
                size_t prow = (size_t)(pair & 1) * N_TOK + (pair >> 1);
                #pragma unroll
                for (int n = 0; n < 4; ++n)
                    Out[prow * HID + cols[n]] = f2bf(acc[m][n][j] + bv[n]);
            }
        }
    }
}

// ---------------- combine: out[n] = w0*P[0][n] + w1*P[1][n]
__global__ __launch_bounds__(256) void combine_moe(
    const unsigned short* __restrict__ P, const float* __restrict__ tk_w,
    float* __restrict__ out)
{
    const int n = blockIdx.x;
    const float w0 = tk_w[n*2], w1 = tk_w[n*2+1];
    const int c = threadIdx.x * 8;
    bf16x8 a = *(const bf16x8*)(P + (size_t)n * HID + c);
    bf16x8 b = *(const bf16x8*)(P + (size_t)(N_TOK + n) * HID + c);
    float4 o0, o1;
    float* op = &o0.x;
    #pragma unroll
    for (int i = 0; i < 4; ++i)
        op[i] = w0 * bf2f((unsigned short)a[i]) + w1 * bf2f((unsigned short)b[i]);
    float* op1 = &o1.x;
    #pragma unroll
    for (int i = 0; i < 4; ++i)
        op1[i] = w0 * bf2f((unsigned short)a[4+i]) + w1 * bf2f((unsigned short)b[4+i]);
    float4* dst = (float4*)(out + (size_t)n * HID + c);
    dst[0] = o0; dst[1] = o1;
}

extern "C" void kernel_launch(void* const* d_in, const int* in_sizes, int n_in,
                              void* d_out, int out_size, void* d_ws, size_t ws_size,
                              hipStream_t stream)
{
    const float* x  = (const float*)d_in[0];
    const float* Wg = (const float*)d_in[1];
    const float* bg = (const float*)d_in[2];
    const float* W1 = (const float*)d_in[3];
    const float* b1 = (const float*)d_in[4];
    const float* W2 = (const float*)d_in[5];
    const float* b2 = (const float*)d_in[6];

    float* out        = (float*)d_out;                       // [N, HID]
    float* gate_probs = out + (size_t)N_TOK * HID;           // [N, E]
    float* gate_mask  = gate_probs + (size_t)N_TOK * NEXP;   // [N, E]

    // workspace carve; P aliases dead W1t+Xg after GEMM1
    char* p = (char*)d_ws;
    auto carve = [&](size_t bytes) { char* r = p; p += (bytes + 255) & ~(size_t)255; return r; };
    unsigned short* W2t = (unsigned short*)carve((size_t)NEXP*HID*HID*2);  // 64 MB [e][j][h]
    unsigned short* Hb  = (unsigned short*)carve((size_t)MAXROWS*HID*2);   // 72 MB
    unsigned short* W1t = (unsigned short*)carve((size_t)NEXP*DIM*HID*2);  // 32 MB [e][h][d]
    unsigned short* Xg  = (unsigned short*)carve((size_t)MAXROWS*DIM*2);   // 36 MB
    unsigned short* P   = W1t;   // 64 MB alias over W1t+Xg; both dead at GEMM2
    int*   pair_token = (int*)  carve((size_t)MAXROWS*4);
    int*   slot_row   = (int*)  carve((size_t)NPAIR*4);
    int*   tk_e       = (int*)  carve((size_t)NPAIR*4);
    float* tk_w       = (float*)carve((size_t)NPAIR*4);
    int*   sched_e    = (int*)  carve(1024);
    int*   sched_row  = (int*)  carve(1024);
    int*   total_tiles= (int*)  carve(256);

    hipMemsetAsync(pair_token, 0xFF, (size_t)MAXROWS*4, stream);  // -1 = pad

    cvt_transpose_moe<<<dim3(HID/64, DIM/64, NEXP), 256, 0, stream>>>(W1, W1t, DIM, HID);
    cvt_transpose_moe<<<dim3(HID/64, HID/64, NEXP), 256, 0, stream>>>(W2, W2t, HID, HID);
    router_moe<<<N_TOK/4, 256, 0, stream>>>(x, Wg, bg, gate_probs, gate_mask, tk_e, tk_w);
    assign_moe<<<1, 1024, 0, stream>>>(tk_e, slot_row, pair_token,
                                       sched_e, sched_row, total_tiles);
    gather_moe<<<N_TOK, 256, 0, stream>>>(x, slot_row, Xg);
    gemm_moe<DIM, 0><<<dim3(MAXRT, NT_COL), NTHREADS, 0, stream>>>(
        Xg, W1t, b1, sched_e, sched_row, total_tiles, Hb, nullptr);
    gemm_moe<HID, 1><<<dim3(MAXRT, NT_COL), NTHREADS, 0, stream>>>(
        Hb, W2t, b2, sched_e, sched_row, total_tiles, P, pair_token);
    combine_moe<<<N_TOK, 256, 0, stream>>>(P, tk_w, out);
}

// Round 9
// 382.632 us; speedup vs baseline: 6.3716x; 1.0116x over previous
//
#include <hip/hip_runtime.h>

#define N_TOK 8192
#define DIM   1024
#define HID   2048
#define NEXP  8
#define TOPK  2
#define BM 256
#define BK 64
#define NTHREADS 512
#define MAXROWS (N_TOK*TOPK + NEXP*BM)   /* 18432 */
#define MAXRT   (MAXROWS/BM)             /* 72 row tiles */
#define NPAIR   (N_TOK*TOPK)             /* 16384 */

typedef float f32x4 __attribute__((ext_vector_type(4)));
typedef short bf16x8 __attribute__((ext_vector_type(8)));

static __device__ __forceinline__ unsigned short f2bf(float f){
    union { float f; unsigned u; } v; v.f = f;
    unsigned r = v.u + 0x7FFFu + ((v.u >> 16) & 1u);
    return (unsigned short)(r >> 16);
}
static __device__ __forceinline__ float bf2f(unsigned short u){
    union { unsigned u; float f; } v; v.u = ((unsigned)u) << 16;
    return v.f;
}

static __device__ __forceinline__ void gload_lds16(const void* g, void* l){
    __builtin_amdgcn_global_load_lds((const __attribute__((address_space(1))) void*)g,
                                     (__attribute__((address_space(3))) void*)l,
                                     16, 0, 0);
}

// ---------------- weight convert + transpose (coalesced):
__global__ __launch_bounds__(256) void cvt_transpose_moe(
    const float* __restrict__ src, unsigned short* __restrict__ dst, int R, int C)
{
    __shared__ float tile[64][65];
    const size_t plane = (size_t)R * C;
    const float* s = src + (size_t)blockIdx.z * plane;
    unsigned short* d = dst + (size_t)blockIdx.z * plane;
    const int c0 = blockIdx.x * 64, r0 = blockIdx.y * 64;
    const int tq = threadIdx.x & 15, tr = threadIdx.x >> 4;   // 16 x 16
    #pragma unroll
    for (int p = 0; p < 4; ++p) {
        int row = p*16 + tr;
        float4 v = *(const float4*)(s + (size_t)(r0 + row) * C + c0 + tq*4);
        tile[row][tq*4+0] = v.x; tile[row][tq*4+1] = v.y;
        tile[row][tq*4+2] = v.z; tile[row][tq*4+3] = v.w;
    }
    __syncthreads();
    #pragma unroll
    for (int p = 0; p < 4; ++p) {
        int orow = p*16 + tr;
        ushort4 o;
        o.x = f2bf(tile[tq*4+0][orow]);
        o.y = f2bf(tile[tq*4+1][orow]);
        o.z = f2bf(tile[tq*4+2][orow]);
        o.w = f2bf(tile[tq*4+3][orow]);
        *(ushort4*)(d + (size_t)(c0 + orow) * R + r0 + tq*4) = o;
    }
}

// ---------------- router: 1 wave per token (NO atomics)
__global__ __launch_bounds__(256) void router_moe(
    const float* __restrict__ x, const float* __restrict__ Wg, const float* __restrict__ bg,
    float* __restrict__ gate_probs, float* __restrict__ gate_mask,
    int* __restrict__ tk_e, float* __restrict__ tk_w)
{
    const int lane = threadIdx.x & 63;
    const int n = blockIdx.x * 4 + (threadIdx.x >> 6);
    const float* xr = x + (size_t)n * DIM;

    float acc[NEXP];
    #pragma unroll
    for (int e = 0; e < NEXP; ++e) acc[e] = 0.f;
    #pragma unroll 4
    for (int i = 0; i < DIM/64; ++i) {
        int d = i*64 + lane;
        float xv = xr[d];
        const float4* wrow = (const float4*)(Wg + (size_t)d * NEXP);
        float4 w0 = wrow[0], w1 = wrow[1];
        acc[0] += xv*w0.x; acc[1] += xv*w0.y; acc[2] += xv*w0.z; acc[3] += xv*w0.w;
        acc[4] += xv*w1.x; acc[5] += xv*w1.y; acc[6] += xv*w1.z; acc[7] += xv*w1.w;
    }
    #pragma unroll
    for (int off = 32; off > 0; off >>= 1) {
        #pragma unroll
        for (int e = 0; e < NEXP; ++e) acc[e] += __shfl_xor(acc[e], off, 64);
    }
    float lgt[NEXP];
    float mx = acc[0] + bg[0];
    #pragma unroll
    for (int e = 0; e < NEXP; ++e) { lgt[e] = acc[e] + bg[e]; mx = fmaxf(mx, lgt[e]); }
    float s = 0.f;
    #pragma unroll
    for (int e = 0; e < NEXP; ++e) { lgt[e] = expf(lgt[e] - mx); s += lgt[e]; }
    float inv = 1.f / s;
    #pragma unroll
    for (int e = 0; e < NEXP; ++e) lgt[e] *= inv;

    int i1 = 0;
    #pragma unroll
    for (int e = 1; e < NEXP; ++e) if (lgt[e] > lgt[i1]) i1 = e;
    int i2 = (i1 == 0) ? 1 : 0;
    #pragma unroll
    for (int e = 0; e < NEXP; ++e) if (e != i1 && lgt[e] > lgt[i2]) i2 = e;
    float wsum = lgt[i1] + lgt[i2] + 1e-8f;
    float w1n = lgt[i1] / wsum, w2n = lgt[i2] / wsum;

    if (lane < NEXP) {
        gate_probs[(size_t)n*NEXP + lane] = lgt[lane];
        gate_mask [(size_t)n*NEXP + lane] = (lane == i1) ? w1n : (lane == i2) ? w2n : 0.f;
    }
    if (lane == 0) {
        tk_e[n*TOPK]   = i1; tk_e[n*TOPK+1] = i2;
        tk_w[n*TOPK]   = w1n; tk_w[n*TOPK+1] = w2n;
    }
}

// ---------------- assign: single block, 16 waves, ballot-histogram slotting
__global__ __launch_bounds__(1024) void assign_moe(
    const int* __restrict__ tk_e,
    int* __restrict__ slot_row, int* __restrict__ pair_token,
    int* __restrict__ sched_e, int* __restrict__ sched_row,
    int* __restrict__ total_tiles)
{
    __shared__ int whist[16][NEXP];
    __shared__ int wbase[16][NEXP];
    const int w = threadIdx.x >> 6, lane = threadIdx.x & 63;
    const int PW = NPAIR / 16;
    const unsigned long long below = ((unsigned long long)1 << lane) - 1;

    int h[NEXP] = {0,0,0,0,0,0,0,0};
    for (int i = 0; i < PW/64; ++i) {
        int e = tk_e[w*PW + i*64 + lane];
        #pragma unroll
        for (int ee = 0; ee < NEXP; ++ee)
            h[ee] += __popcll(__ballot(e == ee));
    }
    if (lane == 0) {
        #pragma unroll
        for (int ee = 0; ee < NEXP; ++ee) whist[w][ee] = h[ee];
    }
    __syncthreads();

    if (threadIdx.x == 0) {
        int base = 0, t = 0, ebase[NEXP];
        for (int e = 0; e < NEXP; ++e) {
            int c = 0;
            for (int ww = 0; ww < 16; ++ww) c += whist[ww][e];
            ebase[e] = base;
            int nt = (c + BM - 1) / BM;
            for (int i = 0; i < nt; ++i) { sched_e[t] = e; sched_row[t] = base + i*BM; ++t; }
            base += nt * BM;
        }
        *total_tiles = t;
        for (int e = 0; e < NEXP; ++e) {
            int r = ebase[e];
            for (int ww = 0; ww < 16; ++ww) { wbase[ww][e] = r; r += whist[ww][e]; }
        }
    }
    __syncthreads();

    int run[NEXP];
    #pragma unroll
    for (int ee = 0; ee < NEXP; ++ee) run[ee] = wbase[w][ee];
    for (int i = 0; i < PW/64; ++i) {
        int idx = w*PW + i*64 + lane;
        int e = tk_e[idx];
        int myslot = 0;
        #pragma unroll
        for (int ee = 0; ee < NEXP; ++ee) {
            unsigned long long m = __ballot(e == ee);
            if (e == ee) myslot = run[ee] + __popcll(m & below);
            run[ee] += __popcll(m);
        }
        slot_row[idx] = myslot;
        pair_token[myslot] = idx;
    }
}

// ---------------- gather: pure copy, slots precomputed
__global__ __launch_bounds__(256) void gather_moe(
    const float* __restrict__ x, const int* __restrict__ slot_row,
    unsigned short* __restrict__ Xg)
{
    const int n = blockIdx.x;
    const int r0 = slot_row[n*TOPK], r1 = slot_row[n*TOPK+1];
    float4 xv = ((const float4*)(x + (size_t)n * DIM))[threadIdx.x];
    ushort4 b;
    b.x = f2bf(xv.x); b.y = f2bf(xv.y); b.z = f2bf(xv.z); b.w = f2bf(xv.w);
    ((ushort4*)(Xg + (size_t)r0 * DIM))[threadIdx.x] = b;
    ((ushort4*)(Xg + (size_t)r1 * DIM))[threadIdx.x] = b;
}

// ======================================================================
// GEMM1 (K=1024): R8 winner — 256x128 tile, 4-phase ring half-slots, 48KB LDS.
// Out = relu(Xg @ W1t^T + b1) -> bf16 Hb rows.
// ======================================================================
#define G1_BN 128
#define G1_NTCOL (HID/G1_BN)   /* 16 */

#define G1_MFMA(MH, NH, BF) do {                                             \
    __builtin_amdgcn_s_setprio(1);                                           \
    _Pragma("unroll")                                                        \
    for (int mi = 0; mi < 2; ++mi)                                           \
        _Pragma("unroll")                                                    \
        for (int nb = 0; nb < 2; ++nb)                                       \
            _Pragma("unroll")                                                \
            for (int kk = 0; kk < 2; ++kk)                                   \
                acc[(MH)*2+mi][(NH)*2+nb] =                                  \
                    __builtin_amdgcn_mfma_f32_16x16x32_bf16(                 \
                        af[mi][kk], BF[nb][kk], acc[(MH)*2+mi][(NH)*2+nb],   \
                        0, 0, 0);                                            \
    __builtin_amdgcn_s_setprio(0);                                           \
} while (0)

__global__ __launch_bounds__(512, 2) void gemm1_moe(
    const unsigned short* __restrict__ A,    // Xg [rows][1024]
    const unsigned short* __restrict__ Bt,   // W1t [E][2048][1024]
    const float* __restrict__ bias,          // b1 [E][2048]
    const int* __restrict__ sched_e, const int* __restrict__ sched_row,
    const int* __restrict__ total_tiles,
    unsigned short* __restrict__ Out)        // Hb [rows][2048]
{
    constexpr int K = DIM;
    const int nwg  = gridDim.x * gridDim.y;
    const int orig = blockIdx.y * gridDim.x + blockIdx.x;
    const int q = nwg >> 3, r8 = nwg & 7, xcd = orig & 7, lin = orig >> 3;
    const int wg = (xcd < r8 ? xcd*(q+1) : r8*(q+1) + (xcd-r8)*q) + lin;
    const int rt = wg / G1_NTCOL, ct = wg % G1_NTCOL;
    if (rt >= *total_tiles) return;

    const int e    = sched_e[rt];
    const int row0 = sched_row[rt];
    const int col0 = ct * G1_BN;
    const unsigned short* Be = Bt + (size_t)e * HID * K;

    __shared__ __align__(1024) char lds[49152];
    char* ldsA = lds;            // 2 half-slots x 16 KB
    char* ldsB = lds + 32768;    // 2 half-slots x 8 KB

    const int tid  = threadIdx.x;
    const int wv   = tid >> 6, lane = tid & 63;
    const int wr   = wv >> 1,  wc   = wv & 1;      // 4 x 2 wave grid, wave 64x64
    const int lrow = lane & 15, lg  = lane >> 4;
    const int sr   = lane >> 3, si  = lane & 7;
    const int gc16 = si ^ sr;

    const unsigned short* Ab = A  + (size_t)row0 * K + gc16 * 8;
    const unsigned short* Bb = Be + (size_t)col0 * K + gc16 * 8;

    f32x4 acc[4][4] = {};
    bf16x8 af[2][2], b0f[2][2], b1f[2][2];

    auto STAGE_A = [&](int h, int t) {             // 2 loads/thread
        char* dst = ldsA + h*16384;
        #pragma unroll
        for (int j = 0; j < 2; ++j) {
            int c = wv*2 + j;
            int idx = c*8 + sr;
            int r = ((idx>>5)<<6) + h*32 + (idx&31);
            gload_lds16(Ab + (size_t)r * K + t*BK, dst + c*1024);
        }
    };
    auto STAGE_B = [&](int h, int t) {             // 1 load/thread
        char* dst = ldsB + h*8192;
        int c = wv;
        int idx = c*8 + sr;
        int gcol = ((idx>>5)<<6) + h*32 + (idx&31);
        gload_lds16(Bb + (size_t)gcol * K + t*BK, dst + c*1024);
    };
    auto RD_A = [&](int mh) {
        const char* base = ldsA + mh*16384;
        #pragma unroll
        for (int mi = 0; mi < 2; ++mi) {
            int idx = wr*32 + mi*16 + lrow;
            #pragma unroll
            for (int kk = 0; kk < 2; ++kk) {
                int s = (kk*4 + lg) ^ (idx & 7);
                af[mi][kk] = *(const bf16x8*)(base + idx*128 + s*16);
            }
        }
    };
    auto RD_B = [&](int nh, bf16x8 (*bf)[2]) {
        const char* base = ldsB + nh*8192;
        #pragma unroll
        for (int nb = 0; nb < 2; ++nb) {
            int idx = wc*32 + nb*16 + lrow;
            #pragma unroll
            for (int kk = 0; kk < 2; ++kk) {
                int s = (kk*4 + lg) ^ (idx & 7);
                bf[nb][kk] = *(const bf16x8*)(base + idx*128 + s*16);
            }
        }
    };
    auto BARRIER = [&]() {
        __builtin_amdgcn_sched_barrier(0);
        __builtin_amdgcn_s_barrier();
        __builtin_amdgcn_sched_barrier(0);
    };
    auto LGKM0 = [&]() {
        asm volatile("s_waitcnt lgkmcnt(0)" ::: "memory");
        __builtin_amdgcn_sched_barrier(0);
    };

    constexpr int NT = K / BK;

    STAGE_A(0, 0); STAGE_B(0, 0); STAGE_B(1, 0); STAGE_A(1, 0);
    asm volatile("s_waitcnt vmcnt(3)" ::: "memory");
    BARRIER();

    for (int t = 0; t < NT; ++t) {
        const bool pf = (t + 1 < NT);
        RD_A(0); RD_B(0, b0f);
        BARRIER(); LGKM0();
        G1_MFMA(0,0,b0f);
        asm volatile("s_waitcnt vmcnt(2)" ::: "memory");
        BARRIER();
        RD_B(1, b1f);
        if (pf) { STAGE_A(0, t+1); STAGE_B(0, t+1); }
        BARRIER(); LGKM0();
        G1_MFMA(0,1,b1f);
        if (pf) { asm volatile("s_waitcnt vmcnt(3)" ::: "memory"); }
        else    { asm volatile("s_waitcnt vmcnt(0)" ::: "memory"); }
        BARRIER();
        RD_A(1);
        if (pf) STAGE_B(1, t+1);
        BARRIER(); LGKM0();
        G1_MFMA(1,0,b0f);
        BARRIER();
        if (pf) STAGE_A(1, t+1);
        BARRIER();
        G1_MFMA(1,1,b1f);
        if (pf) { asm volatile("s_waitcnt vmcnt(3)" ::: "memory"); BARRIER(); }
    }

    #pragma unroll
    for (int n = 0; n < 4; ++n) {
        int col = col0 + wc*64 + ((n>>1)<<5) + ((n&1)<<4) + lrow;
        float bv = bias[(size_t)e*HID + col];
        #pragma unroll
        for (int m = 0; m < 4; ++m) {
            int rb = row0 + wr*64 + ((m>>1)<<5) + ((m&1)<<4) + lg*4;
            #pragma unroll
            for (int j = 0; j < 4; ++j) {
                float v = fmaxf(acc[m][n][j] + bv, 0.f);
                Out[(size_t)(rb + j) * HID + col] = f2bf(v);
            }
        }
    }
}

// ======================================================================
// GEMM2 (K=2048): R5/R6 winner — 256x256 tile, quadrant 8-phase, 128KB LDS.
// P[pair] = Hb @ W2t^T + b2 -> bf16 token-slot scatter.
// ======================================================================
#define G2_BN 256
#define G2_NTCOL (HID/G2_BN)   /* 8 */

#define G2_MFMA(MH, NH, BF) do {                                             \
    __builtin_amdgcn_s_setprio(1);                                           \
    _Pragma("unroll")                                                        \
    for (int mi = 0; mi < 4; ++mi)                                           \
        _Pragma("unroll")                                                    \
        for (int nb = 0; nb < 2; ++nb)                                       \
            _Pragma("unroll")                                                \
            for (int kk = 0; kk < 2; ++kk)                                   \
                acc[(MH)*4+mi][(NH)*2+nb] =                                  \
                    __builtin_amdgcn_mfma_f32_16x16x32_bf16(                 \
                        af[mi][kk], BF[nb][kk], acc[(MH)*4+mi][(NH)*2+nb],   \
                        0, 0, 0);                                            \
    __builtin_amdgcn_s_setprio(0);                                           \
} while (0)

__global__ __launch_bounds__(512, 1) void gemm2_moe(
    const unsigned short* __restrict__ A,    // Hb [rows][2048]
    const unsigned short* __restrict__ Bt,   // W2t [E][2048][2048]
    const float* __restrict__ bias,          // b2 [E][2048]
    const int* __restrict__ sched_e, const int* __restrict__ sched_row,
    const int* __restrict__ total_tiles,
    unsigned short* __restrict__ Out,        // P [2][N][2048]
    const int* __restrict__ pair_token)
{
    constexpr int K = HID;
    const int nwg  = gridDim.x * gridDim.y;
    const int orig = blockIdx.y * gridDim.x + blockIdx.x;
    const int q = nwg >> 3, r8 = nwg & 7, xcd = orig & 7, lin = orig >> 3;
    const int wg = (xcd < r8 ? xcd*(q+1) : r8*(q+1) + (xcd-r8)*q) + lin;
    const int rt = wg / G2_NTCOL, ct = wg % G2_NTCOL;
    if (rt >= *total_tiles) return;

    const int e    = sched_e[rt];
    const int row0 = sched_row[rt];
    const int col0 = ct * G2_BN;
    const unsigned short* Be = Bt + (size_t)e * HID * K;

    __shared__ __align__(1024) char lds[131072];
    char* ldsA = lds;            // [2 buf][2 half][16 KB]
    char* ldsB = lds + 65536;

    const int tid  = threadIdx.x;
    const int wv   = tid >> 6, lane = tid & 63;
    const int wr   = wv >> 2,  wc   = wv & 3;      // 2 x 4 wave grid, wave 128x64
    const int lrow = lane & 15, lg  = lane >> 4;
    const int sr   = lane >> 3, si  = lane & 7;
    const int gc16 = si ^ sr;

    const unsigned short* Ab = A  + (size_t)row0 * K + gc16 * 8;
    const unsigned short* Bb = Be + (size_t)col0 * K + gc16 * 8;

    f32x4 acc[8][4] = {};
    bf16x8 af[4][2], b0f[2][2], b1f[2][2];

    auto STAGE_A = [&](int buf, int h, int t) {
        char* dst = ldsA + (buf*2 + h)*16384;
        #pragma unroll
        for (int j = 0; j < 2; ++j) {
            int c = wv*2 + j;
            int r = ((c>>3)<<7) + h*64 + ((c&7)<<3) + sr;
            gload_lds16(Ab + (size_t)r * K + t*BK, dst + c*1024);
        }
    };
    auto STAGE_B = [&](int buf, int h, int t) {
        char* dst = ldsB + (buf*2 + h)*16384;
        #pragma unroll
        for (int j = 0; j < 2; ++j) {
            int c = wv*2 + j;
            int idx = c*8 + sr;
            int gcol = ((idx>>5)<<6) + h*32 + (idx&31);
            gload_lds16(Bb + (size_t)gcol * K + t*BK, dst + c*1024);
        }
    };
    auto RD_A = [&](int buf, int mh) {
        const char* base = ldsA + (buf*2 + mh)*16384;
        #pragma unroll
        for (int mi = 0; mi < 4; ++mi) {
            int idx = wr*64 + mi*16 + lrow;
            #pragma unroll
            for (int kk = 0; kk < 2; ++kk) {
                int s = (kk*4 + lg) ^ (idx & 7);
                af[mi][kk] = *(const bf16x8*)(base + idx*128 + s*16);
            }
        }
    };
    auto RD_B = [&](int buf, int nh, bf16x8 (*bf)[2]) {
        const char* base = ldsB + (buf*2 + nh)*16384;
        #pragma unroll
        for (int nb = 0; nb < 2; ++nb) {
            int idx = wc*32 + nb*16 + lrow;
            #pragma unroll
            for (int kk = 0; kk < 2; ++kk) {
                int s = (kk*4 + lg) ^ (idx & 7);
                bf[nb][kk] = *(const bf16x8*)(base + idx*128 + s*16);
            }
        }
    };
    auto BARRIER = [&]() {
        __builtin_amdgcn_sched_barrier(0);
        __builtin_amdgcn_s_barrier();
        __builtin_amdgcn_sched_barrier(0);
    };
    auto LGKM0 = [&]() {
        asm volatile("s_waitcnt lgkmcnt(0)" ::: "memory");
        __builtin_amdgcn_sched_barrier(0);
    };

    constexpr int NT = K / BK;
    constexpr int NI = NT / 2;
    static_assert(NT % 2 == 0, "even K-tiles required");

    STAGE_A(0,0,0); STAGE_B(0,0,0); STAGE_A(0,1,0); STAGE_B(0,1,0);
    STAGE_A(1,0,1); STAGE_B(1,0,1);
    asm volatile("s_waitcnt vmcnt(4)" ::: "memory");
    BARRIER();

    for (int i = 0; i < NI; ++i) {
        const int ta = 2*i, tb = 2*i + 1;
        const bool pf = (i + 1 < NI);
        // ---- tile ta (buf0) ----
        RD_A(0,0); RD_B(0,0,b0f);
        STAGE_A(1,1,tb);
        BARRIER(); LGKM0();
        G2_MFMA(0,0,b0f);
        BARRIER();
        RD_B(0,1,b1f);
        STAGE_B(1,1,tb);
        BARRIER(); LGKM0();
        G2_MFMA(0,1,b1f);
        BARRIER();
        RD_A(0,1);
        if (pf) STAGE_A(0,0,ta+2);
        BARRIER(); LGKM0();
        G2_MFMA(1,0,b0f);
        BARRIER();
        if (pf) STAGE_B(0,0,ta+2);
        BARRIER();
        G2_MFMA(1,1,b1f);
        // ledger: pf -> 12 outstanding, vmcnt(4) completes buf1 for tb.
        // last iter: 8 outstanding -> full drain (round-4 race fix).
        if (pf) { asm volatile("s_waitcnt vmcnt(4)" ::: "memory"); }
        else    { asm volatile("s_waitcnt vmcnt(0)" ::: "memory"); }
        BARRIER();
        // ---- tile tb (buf1) ----
        RD_A(1,0); RD_B(1,0,b0f);
        if (pf) STAGE_A(0,1,ta+2);
        BARRIER(); LGKM0();
        G2_MFMA(0,0,b0f);
        BARRIER();
        RD_B(1,1,b1f);
        if (pf) STAGE_B(0,1,ta+2);
        BARRIER(); LGKM0();
        G2_MFMA(0,1,b1f);
        BARRIER();
        RD_A(1,1);
        if (pf) STAGE_A(1,0,tb+2);
        BARRIER(); LGKM0();
        G2_MFMA(1,0,b0f);
        BARRIER();
        if (pf) STAGE_B(1,0,tb+2);
        BARRIER();
        G2_MFMA(1,1,b1f);
        if (pf) { asm volatile("s_waitcnt vmcnt(4)" ::: "memory"); BARRIER(); }
    }

    float bv[4]; int cols[4];
    #pragma unroll
    for (int nb = 0; nb < 4; ++nb) {
        cols[nb] = col0 + wc*64 + nb*16 + lrow;
        bv[nb] = bias[(size_t)e*HID + cols[nb]];
    }
    #pragma unroll
    for (int mb = 0; mb < 8; ++mb) {
        #pragma unroll
        for (int j = 0; j < 4; ++j) {
            int r = row0 + wr*128 + mb*16 + lg*4 + j;
            int pair = pair_token[r];
            if (pair < 0) continue;
            size_t prow = (size_t)(pair & 1) * N_TOK + (pair >> 1);
            #pragma unroll
            for (int nb = 0; nb < 4; ++nb)
                Out[prow * HID + cols[nb]] = f2bf(acc[mb][nb][j] + bv[nb]);
        }
    }
}

// ---------------- combine: out[n] = w0*P[0][n] + w1*P[1][n]
__global__ __launch_bounds__(256) void combine_moe(
    const unsigned short* __restrict__ P, const float* __restrict__ tk_w,
    float* __restrict__ out)
{
    const int n = blockIdx.x;
    const float w0 = tk_w[n*2], w1 = tk_w[n*2+1];
    const int c = threadIdx.x * 8;
    bf16x8 a = *(const bf16x8*)(P + (size_t)n * HID + c);
    bf16x8 b = *(const bf16x8*)(P + (size_t)(N_TOK + n) * HID + c);
    float4 o0, o1;
    float* op = &o0.x;
    #pragma unroll
    for (int i = 0; i < 4; ++i)
        op[i] = w0 * bf2f((unsigned short)a[i]) + w1 * bf2f((unsigned short)b[i]);
    float* op1 = &o1.x;
    #pragma unroll
    for (int i = 0; i < 4; ++i)
        op1[i] = w0 * bf2f((unsigned short)a[4+i]) + w1 * bf2f((unsigned short)b[4+i]);
    float4* dst = (float4*)(out + (size_t)n * HID + c);
    dst[0] = o0; dst[1] = o1;
}

extern "C" void kernel_launch(void* const* d_in, const int* in_sizes, int n_in,
                              void* d_out, int out_size, void* d_ws, size_t ws_size,
                              hipStream_t stream)
{
    const float* x  = (const float*)d_in[0];
    const float* Wg = (const float*)d_in[1];
    const float* bg = (const float*)d_in[2];
    const float* W1 = (const float*)d_in[3];
    const float* b1 = (const float*)d_in[4];
    const float* W2 = (const float*)d_in[5];
    const float* b2 = (const float*)d_in[6];

    float* out        = (float*)d_out;                       // [N, HID]
    float* gate_probs = out + (size_t)N_TOK * HID;           // [N, E]
    float* gate_mask  = gate_probs + (size_t)N_TOK * NEXP;   // [N, E]

    // workspace carve; P aliases dead W1t+Xg after GEMM1
    char* p = (char*)d_ws;
    auto carve = [&](size_t bytes) { char* r = p; p += (bytes + 255) & ~(size_t)255; return r; };
    unsigned short* W2t = (unsigned short*)carve((size_t)NEXP*HID*HID*2);  // 64 MB
    unsigned short* Hb  = (unsigned short*)carve((size_t)MAXROWS*HID*2);   // 72 MB
    unsigned short* W1t = (unsigned short*)carve((size_t)NEXP*DIM*HID*2);  // 32 MB
    unsigned short* Xg  = (unsigned short*)carve((size_t)MAXROWS*DIM*2);   // 36 MB
    unsigned short* P   = W1t;   // 64 MB alias over W1t+Xg; both dead at GEMM2
    int*   pair_token = (int*)  carve((size_t)MAXROWS*4);
    int*   slot_row   = (int*)  carve((size_t)NPAIR*4);
    int*   tk_e       = (int*)  carve((size_t)NPAIR*4);
    float* tk_w       = (float*)carve((size_t)NPAIR*4);
    int*   sched_e    = (int*)  carve(1024);
    int*   sched_row  = (int*)  carve(1024);
    int*   total_tiles= (int*)  carve(256);

    hipMemsetAsync(pair_token, 0xFF, (size_t)MAXROWS*4, stream);  // -1 = pad

    cvt_transpose_moe<<<dim3(HID/64, DIM/64, NEXP), 256, 0, stream>>>(W1, W1t, DIM, HID);
    cvt_transpose_moe<<<dim3(HID/64, HID/64, NEXP), 256, 0, stream>>>(W2, W2t, HID, HID);
    router_moe<<<N_TOK/4, 256, 0, stream>>>(x, Wg, bg, gate_probs, gate_mask, tk_e, tk_w);
    assign_moe<<<1, 1024, 0, stream>>>(tk_e, slot_row, pair_token,
                                       sched_e, sched_row, total_tiles);
    gather_moe<<<N_TOK, 256, 0, stream>>>(x, slot_row, Xg);
    gemm1_moe<<<dim3(MAXRT, G1_NTCOL), NTHREADS, 0, stream>>>(
        Xg, W1t, b1, sched_e, sched_row, total_tiles, Hb);
    gemm2_moe<<<dim3(MAXRT, G2_NTCOL), NTHREADS, 0, stream>>>(
        Hb, W2t, b2, sched_e, sched_row, total_tiles, P, pair_token);
    combine_moe<<<N_TOK, 256, 0, stream>>>(P, tk_w, out);
}

// Round 10
// 348.358 us; speedup vs baseline: 6.9985x; 1.0984x over previous
//
#include <hip/hip_runtime.h>

#define N_TOK 8192
#define DIM   1024
#define HID   2048
#define NEXP  8
#define TOPK  2
#define BM 128
#define BN 128
#define BK 64
#define NTHREADS 256
#define MAXROWS (N_TOK*TOPK + NEXP*BM)   /* 17408 */
#define MAXRT   (MAXROWS/BM)             /* 136 row tiles */
#define NT_COL  (HID/BN)                 /* 16 col tiles */
#define NPAIR   (N_TOK*TOPK)             /* 16384 */

typedef float f32x4 __attribute__((ext_vector_type(4)));
typedef short bf16x8 __attribute__((ext_vector_type(8)));

static __device__ __forceinline__ unsigned short f2bf(float f){
    union { float f; unsigned u; } v; v.f = f;
    unsigned r = v.u + 0x7FFFu + ((v.u >> 16) & 1u);
    return (unsigned short)(r >> 16);
}
static __device__ __forceinline__ float bf2f(unsigned short u){
    union { unsigned u; float f; } v; v.u = ((unsigned)u) << 16;
    return v.f;
}

static __device__ __forceinline__ void gload_lds16(const void* g, void* l){
    __builtin_amdgcn_global_load_lds((const __attribute__((address_space(1))) void*)g,
                                     (__attribute__((address_space(3))) void*)l,
                                     16, 0, 0);
}

// ---------------- weight convert + transpose (coalesced):
__global__ __launch_bounds__(256) void cvt_transpose_moe(
    const float* __restrict__ src, unsigned short* __restrict__ dst, int R, int C)
{
    __shared__ float tile[64][65];
    const size_t plane = (size_t)R * C;
    const float* s = src + (size_t)blockIdx.z * plane;
    unsigned short* d = dst + (size_t)blockIdx.z * plane;
    const int c0 = blockIdx.x * 64, r0 = blockIdx.y * 64;
    const int tq = threadIdx.x & 15, tr = threadIdx.x >> 4;   // 16 x 16
    #pragma unroll
    for (int p = 0; p < 4; ++p) {
        int row = p*16 + tr;
        float4 v = *(const float4*)(s + (size_t)(r0 + row) * C + c0 + tq*4);
        tile[row][tq*4+0] = v.x; tile[row][tq*4+1] = v.y;
        tile[row][tq*4+2] = v.z; tile[row][tq*4+3] = v.w;
    }
    __syncthreads();
    #pragma unroll
    for (int p = 0; p < 4; ++p) {
        int orow = p*16 + tr;
        ushort4 o;
        o.x = f2bf(tile[tq*4+0][orow]);
        o.y = f2bf(tile[tq*4+1][orow]);
        o.z = f2bf(tile[tq*4+2][orow]);
        o.w = f2bf(tile[tq*4+3][orow]);
        *(ushort4*)(d + (size_t)(c0 + orow) * R + r0 + tq*4) = o;
    }
}

// ---------------- router: 1 wave per token (NO atomics)
__global__ __launch_bounds__(256) void router_moe(
    const float* __restrict__ x, const float* __restrict__ Wg, const float* __restrict__ bg,
    float* __restrict__ gate_probs, float* __restrict__ gate_mask,
    int* __restrict__ tk_e, float* __restrict__ tk_w)
{
    const int lane = threadIdx.x & 63;
    const int n = blockIdx.x * 4 + (threadIdx.x >> 6);
    const float* xr = x + (size_t)n * DIM;

    float acc[NEXP];
    #pragma unroll
    for (int e = 0; e < NEXP; ++e) acc[e] = 0.f;
    #pragma unroll 4
    for (int i = 0; i < DIM/64; ++i) {
        int d = i*64 + lane;
        float xv = xr[d];
        const float4* wrow = (const float4*)(Wg + (size_t)d * NEXP);
        float4 w0 = wrow[0], w1 = wrow[1];
        acc[0] += xv*w0.x; acc[1] += xv*w0.y; acc[2] += xv*w0.z; acc[3] += xv*w0.w;
        acc[4] += xv*w1.x; acc[5] += xv*w1.y; acc[6] += xv*w1.z; acc[7] += xv*w1.w;
    }
    #pragma unroll
    for (int off = 32; off > 0; off >>= 1) {
        #pragma unroll
        for (int e = 0; e < NEXP; ++e) acc[e] += __shfl_xor(acc[e], off, 64);
    }
    float lgt[NEXP];
    float mx = acc[0] + bg[0];
    #pragma unroll
    for (int e = 0; e < NEXP; ++e) { lgt[e] = acc[e] + bg[e]; mx = fmaxf(mx, lgt[e]); }
    float s = 0.f;
    #pragma unroll
    for (int e = 0; e < NEXP; ++e) { lgt[e] = expf(lgt[e] - mx); s += lgt[e]; }
    float inv = 1.f / s;
    #pragma unroll
    for (int e = 0; e < NEXP; ++e) lgt[e] *= inv;

    int i1 = 0;
    #pragma unroll
    for (int e = 1; e < NEXP; ++e) if (lgt[e] > lgt[i1]) i1 = e;
    int i2 = (i1 == 0) ? 1 : 0;
    #pragma unroll
    for (int e = 0; e < NEXP; ++e) if (e != i1 && lgt[e] > lgt[i2]) i2 = e;
    float wsum = lgt[i1] + lgt[i2] + 1e-8f;
    float w1n = lgt[i1] / wsum, w2n = lgt[i2] / wsum;

    if (lane < NEXP) {
        gate_probs[(size_t)n*NEXP + lane] = lgt[lane];
        gate_mask [(size_t)n*NEXP + lane] = (lane == i1) ? w1n : (lane == i2) ? w2n : 0.f;
    }
    if (lane == 0) {
        tk_e[n*TOPK]   = i1; tk_e[n*TOPK+1] = i2;
        tk_w[n*TOPK]   = w1n; tk_w[n*TOPK+1] = w2n;
    }
}

// ---------------- assign: single block, 16 waves, ballot-histogram slotting
__global__ __launch_bounds__(1024) void assign_moe(
    const int* __restrict__ tk_e,
    int* __restrict__ slot_row, int* __restrict__ pair_token,
    int* __restrict__ sched_e, int* __restrict__ sched_row,
    int* __restrict__ total_tiles)
{
    __shared__ int whist[16][NEXP];
    __shared__ int wbase[16][NEXP];
    const int w = threadIdx.x >> 6, lane = threadIdx.x & 63;
    const int PW = NPAIR / 16;
    const unsigned long long below = ((unsigned long long)1 << lane) - 1;

    int h[NEXP] = {0,0,0,0,0,0,0,0};
    for (int i = 0; i < PW/64; ++i) {
        int e = tk_e[w*PW + i*64 + lane];
        #pragma unroll
        for (int ee = 0; ee < NEXP; ++ee)
            h[ee] += __popcll(__ballot(e == ee));
    }
    if (lane == 0) {
        #pragma unroll
        for (int ee = 0; ee < NEXP; ++ee) whist[w][ee] = h[ee];
    }
    __syncthreads();

    if (threadIdx.x == 0) {
        int base = 0, t = 0, ebase[NEXP];
        for (int e = 0; e < NEXP; ++e) {
            int c = 0;
            for (int ww = 0; ww < 16; ++ww) c += whist[ww][e];
            ebase[e] = base;
            int nt = (c + BM - 1) / BM;
            for (int i = 0; i < nt; ++i) { sched_e[t] = e; sched_row[t] = base + i*BM; ++t; }
            base += nt * BM;
        }
        *total_tiles = t;
        for (int e = 0; e < NEXP; ++e) {
            int r = ebase[e];
            for (int ww = 0; ww < 16; ++ww) { wbase[ww][e] = r; r += whist[ww][e]; }
        }
    }
    __syncthreads();

    int run[NEXP];
    #pragma unroll
    for (int ee = 0; ee < NEXP; ++ee) run[ee] = wbase[w][ee];
    for (int i = 0; i < PW/64; ++i) {
        int idx = w*PW + i*64 + lane;
        int e = tk_e[idx];
        int myslot = 0;
        #pragma unroll
        for (int ee = 0; ee < NEXP; ++ee) {
            unsigned long long m = __ballot(e == ee);
            if (e == ee) myslot = run[ee] + __popcll(m & below);
            run[ee] += __popcll(m);
        }
        slot_row[idx] = myslot;
        pair_token[myslot] = idx;
    }
}

// ---------------- gather: pure copy, slots precomputed
__global__ __launch_bounds__(256) void gather_moe(
    const float* __restrict__ x, const int* __restrict__ slot_row,
    unsigned short* __restrict__ Xg)
{
    const int n = blockIdx.x;
    const int r0 = slot_row[n*TOPK], r1 = slot_row[n*TOPK+1];
    float4 xv = ((const float4*)(x + (size_t)n * DIM))[threadIdx.x];
    ushort4 b;
    b.x = f2bf(xv.x); b.y = f2bf(xv.y); b.z = f2bf(xv.z); b.w = f2bf(xv.w);
    ((ushort4*)(Xg + (size_t)r0 * DIM))[threadIdx.x] = b;
    ((ushort4*)(Xg + (size_t)r1 * DIM))[threadIdx.x] = b;
}

// ======================================================================
// Grouped GEMM: 128x128 tile, 4 waves (wave out 64x64), 4-phase ring
// half-slots, 32 KB LDS, 3 blocks/CU (launch_bounds(256,3): 170-reg cap,
// kernel needs ~136 incl. 64 AGPR acc).
// Halves by bit5: A-half mh = rows with bit5==mh (64 rows, 8KB slot);
// B-half nh likewise. Per-thread loads: STAGE_A = 2, STAGE_B = 2.
// Ledger (steady tile t, per thread):
//   prologue: issue A0(2) B0(2) B1(2) A1(2); vmcnt(4) -> A0,B0 done
//   p0: no stage.                 p0end vmcnt(2) -> B1(t) ready
//   p1: stage A0(t+1)2 B0(t+1)2.  p1end vmcnt(4) -> A1(t) ready  [last: vmcnt(0)]
//   p2: stage B1(t+1)2.           no wait
//   p3: stage A1(t+1)2.           p3end vmcnt(4) -> A0,B0(t+1) ready
// Invariant entering p0: 4 outstanding (= prologue state).
// MODE 0: Out = relu(A@Bt^T + bias), linear rows. MODE 1: token-slot scatter.
// ======================================================================
#define G_MFMA(MH, NH, BF) do {                                              \
    __builtin_amdgcn_s_setprio(1);                                           \
    _Pragma("unroll")                                                        \
    for (int mi = 0; mi < 2; ++mi)                                           \
        _Pragma("unroll")                                                    \
        for (int nb = 0; nb < 2; ++nb)                                       \
            _Pragma("unroll")                                                \
            for (int kk = 0; kk < 2; ++kk)                                   \
                acc[(MH)*2+mi][(NH)*2+nb] =                                  \
                    __builtin_amdgcn_mfma_f32_16x16x32_bf16(                 \
                        af[mi][kk], BF[nb][kk], acc[(MH)*2+mi][(NH)*2+nb],   \
                        0, 0, 0);                                            \
    __builtin_amdgcn_s_setprio(0);                                           \
} while (0)

template<int K, int MODE>
__global__ __launch_bounds__(256, 3) void gemm_moe(
    const unsigned short* __restrict__ A,    // [rows][K] bf16
    const unsigned short* __restrict__ Bt,   // [E][HID][K] bf16
    const float* __restrict__ bias,          // [E][HID]
    const int* __restrict__ sched_e, const int* __restrict__ sched_row,
    const int* __restrict__ total_tiles,
    unsigned short* __restrict__ Out,
    const int* __restrict__ pair_token)
{
    // T1: bijective XCD swizzle (2176 % 8 == 0)
    const int nwg  = gridDim.x * gridDim.y;
    const int orig = blockIdx.y * gridDim.x + blockIdx.x;
    const int q = nwg >> 3, r8 = nwg & 7, xcd = orig & 7, lin = orig >> 3;
    const int wg = (xcd < r8 ? xcd*(q+1) : r8*(q+1) + (xcd-r8)*q) + lin;
    const int rt = wg / NT_COL, ct = wg % NT_COL;
    if (rt >= *total_tiles) return;

    const int e    = sched_e[rt];
    const int row0 = sched_row[rt];
    const int col0 = ct * BN;
    const unsigned short* Be = Bt + (size_t)e * HID * K;

    __shared__ __align__(1024) char lds[32768];
    char* ldsA = lds;            // 2 half-slots x 8 KB (64 idx x 128 B)
    char* ldsB = lds + 16384;    // 2 half-slots x 8 KB

    const int tid  = threadIdx.x;
    const int wv   = tid >> 6, lane = tid & 63;
    const int wr   = wv >> 1,  wc   = wv & 1;      // 2 x 2 wave grid, wave 64x64
    const int lrow = lane & 15, lg  = lane >> 4;
    const int sr   = lane >> 3, si  = lane & 7;
    const int gc16 = si ^ sr;                      // pre-swizzled global 16B slot (T2)

    const unsigned short* Ab = A  + (size_t)row0 * K + gc16 * 8;
    const unsigned short* Bb = Be + (size_t)col0 * K + gc16 * 8;

    f32x4 acc[4][4] = {};
    bf16x8 af[2][2], b0f[2][2], b1f[2][2];

    // half-slot h: 8 chunks of 1KB; idx = c*8+sr in [0,64); row = (idx>>5)*64 + h*32 + (idx&31)
    auto STAGE_A = [&](int h, int t) {             // 2 loads/thread
        char* dst = ldsA + h*8192;
        #pragma unroll
        for (int j = 0; j < 2; ++j) {
            int c = wv*2 + j;
            int idx = c*8 + sr;
            int r = ((idx>>5)<<6) + h*32 + (idx&31);
            gload_lds16(Ab + (size_t)r * K + t*BK, dst + c*1024);
        }
    };
    auto STAGE_B = [&](int h, int t) {             // 2 loads/thread
        char* dst = ldsB + h*8192;
        #pragma unroll
        for (int j = 0; j < 2; ++j) {
            int c = wv*2 + j;
            int idx = c*8 + sr;
            int gcol = ((idx>>5)<<6) + h*32 + (idx&31);
            gload_lds16(Bb + (size_t)gcol * K + t*BK, dst + c*1024);
        }
    };
    auto RD_A = [&](int mh) {                      // 4 ds_read_b128
        const char* base = ldsA + mh*8192;
        #pragma unroll
        for (int mi = 0; mi < 2; ++mi) {
            int idx = wr*32 + mi*16 + lrow;
            #pragma unroll
            for (int kk = 0; kk < 2; ++kk) {
                int s = (kk*4 + lg) ^ (idx & 7);
                af[mi][kk] = *(const bf16x8*)(base + idx*128 + s*16);
            }
        }
    };
    auto RD_B = [&](int nh, bf16x8 (*bf)[2]) {     // 4 ds_read_b128
        const char* base = ldsB + nh*8192;
        #pragma unroll
        for (int nb = 0; nb < 2; ++nb) {
            int idx = wc*32 + nb*16 + lrow;
            #pragma unroll
            for (int kk = 0; kk < 2; ++kk) {
                int s = (kk*4 + lg) ^ (idx & 7);
                bf[nb][kk] = *(const bf16x8*)(base + idx*128 + s*16);
            }
        }
    };
    auto BARRIER = [&]() {
        __builtin_amdgcn_sched_barrier(0);
        __builtin_amdgcn_s_barrier();
        __builtin_amdgcn_sched_barrier(0);
    };
    auto LGKM0 = [&]() {
        asm volatile("s_waitcnt lgkmcnt(0)" ::: "memory");
        __builtin_amdgcn_sched_barrier(0);
    };

    constexpr int NT = K / BK;
    static_assert(NT >= 2, "need >=2 K-tiles");

    // prologue: issue [A0(2) B0(2) B1(2) A1(2)]; drain first 4 (A0,B0)
    STAGE_A(0, 0); STAGE_B(0, 0); STAGE_B(1, 0); STAGE_A(1, 0);
    asm volatile("s_waitcnt vmcnt(4)" ::: "memory");
    BARRIER();

    for (int t = 0; t < NT; ++t) {
        const bool pf = (t + 1 < NT);
        // p0: Q(mh0,nh0)
        RD_A(0); RD_B(0, b0f);
        BARRIER(); LGKM0();
        G_MFMA(0,0,b0f);
        asm volatile("s_waitcnt vmcnt(2)" ::: "memory");   // B1(t) ready
        BARRIER();
        // p1: Q(mh0,nh1); slots A0/B0 fully read at p0 -> restage for t+1
        RD_B(1, b1f);
        if (pf) { STAGE_A(0, t+1); STAGE_B(0, t+1); }
        BARRIER(); LGKM0();
        G_MFMA(0,1,b1f);
        if (pf) { asm volatile("s_waitcnt vmcnt(4)" ::: "memory"); }  // A1(t) ready
        else    { asm volatile("s_waitcnt vmcnt(0)" ::: "memory"); }
        BARRIER();
        // p2: Q(mh1,nh0); slot B1 free -> stage B1(t+1)
        RD_A(1);
        if (pf) STAGE_B(1, t+1);
        BARRIER(); LGKM0();
        G_MFMA(1,0,b0f);
        BARRIER();
        // p3: Q(mh1,nh1); slot A1 free -> stage A1(t+1)
        if (pf) STAGE_A(1, t+1);
        BARRIER();
        G_MFMA(1,1,b1f);
        if (pf) { asm volatile("s_waitcnt vmcnt(4)" ::: "memory"); BARRIER(); }
    }

    // epilogue: acc[m][n] -> row = wr*64 + (m>>1)*32 + (m&1)*16 + lg*4 + j
    //                       col = wc*64 + (n>>1)*32 + (n&1)*16 + lrow
    if constexpr (MODE == 0) {
        #pragma unroll
        for (int n = 0; n < 4; ++n) {
            int col = col0 + wc*64 + ((n>>1)<<5) + ((n&1)<<4) + lrow;
            float bv = bias[(size_t)e*HID + col];
            #pragma unroll
            for (int m = 0; m < 4; ++m) {
                int rb = row0 + wr*64 + ((m>>1)<<5) + ((m&1)<<4) + lg*4;
                #pragma unroll
                for (int j = 0; j < 4; ++j) {
                    float v = fmaxf(acc[m][n][j] + bv, 0.f);
                    Out[(size_t)(rb + j) * HID + col] = f2bf(v);
                }
            }
        }
    } else {
        float bv[4]; int cols[4];
        #pragma unroll
        for (int n = 0; n < 4; ++n) {
            cols[n] = col0 + wc*64 + ((n>>1)<<5) + ((n&1)<<4) + lrow;
            bv[n] = bias[(size_t)e*HID + cols[n]];
        }
        #pragma unroll
        for (int m = 0; m < 4; ++m) {
            #pragma unroll
            for (int j = 0; j < 4; ++j) {
                int r = row0 + wr*64 + ((m>>1)<<5) + ((m&1)<<4) + lg*4 + j;
                int pair = pair_token[r];
                if (pair < 0) continue;
                size_t prow = (size_t)(pair & 1) * N_TOK + (pair >> 1);
                #pragma unroll
                for (int n = 0; n < 4; ++n)
                    Out[prow * HID + cols[n]] = f2bf(acc[m][n][j] + bv[n]);
            }
        }
    }
}

// ---------------- combine: out[n] = w0*P[0][n] + w1*P[1][n]
__global__ __launch_bounds__(256) void combine_moe(
    const unsigned short* __restrict__ P, const float* __restrict__ tk_w,
    float* __restrict__ out)
{
    const int n = blockIdx.x;
    const float w0 = tk_w[n*2], w1 = tk_w[n*2+1];
    const int c = threadIdx.x * 8;
    bf16x8 a = *(const bf16x8*)(P + (size_t)n * HID + c);
    bf16x8 b = *(const bf16x8*)(P + (size_t)(N_TOK + n) * HID + c);
    float4 o0, o1;
    float* op = &o0.x;
    #pragma unroll
    for (int i = 0; i < 4; ++i)
        op[i] = w0 * bf2f((unsigned short)a[i]) + w1 * bf2f((unsigned short)b[i]);
    float* op1 = &o1.x;
    #pragma unroll
    for (int i = 0; i < 4; ++i)
        op1[i] = w0 * bf2f((unsigned short)a[4+i]) + w1 * bf2f((unsigned short)b[4+i]);
    float4* dst = (float4*)(out + (size_t)n * HID + c);
    dst[0] = o0; dst[1] = o1;
}

extern "C" void kernel_launch(void* const* d_in, const int* in_sizes, int n_in,
                              void* d_out, int out_size, void* d_ws, size_t ws_size,
                              hipStream_t stream)
{
    const float* x  = (const float*)d_in[0];
    const float* Wg = (const float*)d_in[1];
    const float* bg = (const float*)d_in[2];
    const float* W1 = (const float*)d_in[3];
    const float* b1 = (const float*)d_in[4];
    const float* W2 = (const float*)d_in[5];
    const float* b2 = (const float*)d_in[6];

    float* out        = (float*)d_out;                       // [N, HID]
    float* gate_probs = out + (size_t)N_TOK * HID;           // [N, E]
    float* gate_mask  = gate_probs + (size_t)N_TOK * NEXP;   // [N, E]

    // workspace carve; P aliases dead W1t+Xg after GEMM1
    char* p = (char*)d_ws;
    auto carve = [&](size_t bytes) { char* r = p; p += (bytes + 255) & ~(size_t)255; return r; };
    unsigned short* W2t = (unsigned short*)carve((size_t)NEXP*HID*HID*2);  // 64 MB
    unsigned short* Hb  = (unsigned short*)carve((size_t)MAXROWS*HID*2);   // 71 MB
    unsigned short* W1t = (unsigned short*)carve((size_t)NEXP*DIM*HID*2);  // 32 MB
    unsigned short* Xg  = (unsigned short*)carve((size_t)MAXROWS*DIM*2);   // 36 MB
    unsigned short* P   = W1t;   // 64 MB alias over W1t+Xg; both dead at GEMM2
    int*   pair_token = (int*)  carve((size_t)MAXROWS*4);
    int*   slot_row   = (int*)  carve((size_t)NPAIR*4);
    int*   tk_e       = (int*)  carve((size_t)NPAIR*4);
    float* tk_w       = (float*)carve((size_t)NPAIR*4);
    int*   sched_e    = (int*)  carve(1024);
    int*   sched_row  = (int*)  carve(1024);
    int*   total_tiles= (int*)  carve(256);

    hipMemsetAsync(pair_token, 0xFF, (size_t)MAXROWS*4, stream);  // -1 = pad

    cvt_transpose_moe<<<dim3(HID/64, DIM/64, NEXP), 256, 0, stream>>>(W1, W1t, DIM, HID);
    cvt_transpose_moe<<<dim3(HID/64, HID/64, NEXP), 256, 0, stream>>>(W2, W2t, HID, HID);
    router_moe<<<N_TOK/4, 256, 0, stream>>>(x, Wg, bg, gate_probs, gate_mask, tk_e, tk_w);
    assign_moe<<<1, 1024, 0, stream>>>(tk_e, slot_row, pair_token,
                                       sched_e, sched_row, total_tiles);
    gather_moe<<<N_TOK, 256, 0, stream>>>(x, slot_row, Xg);
    gemm_moe<DIM, 0><<<dim3(MAXRT, NT_COL), NTHREADS, 0, stream>>>(
        Xg, W1t, b1, sched_e, sched_row, total_tiles, Hb, nullptr);
    gemm_moe<HID, 1><<<dim3(MAXRT, NT_COL), NTHREADS, 0, stream>>>(
        Hb, W2t, b2, sched_e, sched_row, total_tiles, P, pair_token);
    combine_moe<<<N_TOK, 256, 0, stream>>>(P, tk_w, out);
}